// Round 2
// baseline (365.929 us; speedup 1.0000x reference)
//
#include <hip/hip_runtime.h>
#include <stdint.h>

// Problem constants
#define B_    2
#define CIN   128
#define HIMG  32
#define WIMG  32
#define COUT_ 128
#define PP    1024          // 32*32 output positions
#define FTOT  1152          // CIN*9
#define NSUB  9
#define CHUNK 128           // features per subarray
#define NS    8             // input bit streams
#define NT    8             // weight bit slices

// Workspace layout (bytes)
#define OFF_NORM   0                      // 128 f32
#define OFF_MAXV   512                    // 18 u32 (atomicMax targets)
#define OFF_STEPS  1024                   // 18 f64
#define OFF_LUT    2048                   // 18*132 u8 = 2376 (pad)
#define OFF_WMASK  8192                   // 9*128*8*2*4 u32 = 294912 B
#define OFF_XMASK  303104                 // 2*9*1024*8*4 u32 = 2359296 B

// ---------------------------------------------------------------------------
// Weight prep: per-o norm, signed int quantization (f64 semantics to match a
// float64 numpy golden), pos/neg 1-bit slices packed into 128-bit masks.
// ---------------------------------------------------------------------------
__global__ __launch_bounds__(256) void k_prep_w(const float* __restrict__ w,
                                                float* __restrict__ norm_out,
                                                uint32_t* __restrict__ wmask) {
    int o = blockIdx.x;
    int tid = threadIdx.x;
    __shared__ float red[256];
    __shared__ uint32_t lmask[NSUB * NT * 2 * 4];   // 576 u32
    for (int i = tid; i < NSUB * NT * 2 * 4; i += 256) lmask[i] = 0u;

    const float* wo = w + (size_t)o * FTOT;
    float m = 0.f;
    for (int f = tid; f < FTOT; f += 256) m = fmaxf(m, fabsf(wo[f]));
    red[tid] = m;
    __syncthreads();
    for (int s = 128; s > 0; s >>= 1) {
        if (tid < s) red[tid] = fmaxf(red[tid], red[tid + s]);
        __syncthreads();
    }
    float norm = red[0];
    if (tid == 0) norm_out[o] = norm;

    for (int f = tid; f < FTOT; f += 256) {
        // f64: round((w/norm)*255), matching a float64 numpy reference;
        // exact-integer bit decomposition below is precision-independent.
        double wi = rint(((double)wo[f] / (double)norm) * 255.0);
        int ip = (int)fmax(wi, 0.0);      // 0..255
        int in_ = (int)fmax(-wi, 0.0);    // 0..255
        int sub = f >> 7;
        int j = f & 127;
        int word = j >> 5, bit = j & 31;
        for (int t = 0; t < NT; ++t) {
            if ((ip >> t) & 1)
                atomicOr(&lmask[((sub * NT + t) * 2 + 0) * 4 + word], 1u << bit);
            if ((in_ >> t) & 1)
                atomicOr(&lmask[((sub * NT + t) * 2 + 1) * 4 + word], 1u << bit);
        }
    }
    __syncthreads();
    // wmask[sub][o][t][sign][word]
    for (int i = tid; i < NSUB * NT * 2 * 4; i += 256) {
        int word = i & 3;
        int sign = (i >> 2) & 1;
        int t = (i >> 3) & 7;
        int sub = i >> 6;
        wmask[(((size_t)sub * COUT_ + o) * NT + t) * 2 * 4 + sign * 4 + word] = lmask[i];
    }
}

// ---------------------------------------------------------------------------
// Input prep: im2col gather + unsigned fixed-point quantize + bit-stream pack.
// xi = round(v*256) is exact in f32 and f64 alike (power-of-two scale).
// ---------------------------------------------------------------------------
__global__ __launch_bounds__(256) void k_prep_x(const float* __restrict__ x,
                                                uint32_t* __restrict__ xmask) {
    int gid = blockIdx.x * 256 + threadIdx.x;    // B_*NSUB*PP = 18432
    if (gid >= B_ * NSUB * PP) return;
    int p = gid & 1023;
    int rest = gid >> 10;
    int sub = rest % NSUB;
    int b = rest / NSUB;
    int py = p >> 5, px = p & 31;

    uint32_t ms[NS][4] = {};
    for (int j = 0; j < CHUNK; ++j) {
        int f = sub * CHUNK + j;
        int c = f / 9;
        int u = f % 9;
        int kh = u / 3, kw = u % 3;
        int y = py + kh - 1, xx = px + kw - 1;
        uint32_t xi = 0;
        if (y >= 0 && y < HIMG && xx >= 0 && xx < WIMG) {
            float v = x[(((size_t)b * CIN + c) * HIMG + y) * WIMG + xx];
            float q = rintf(v * 256.0f);   // exact: *256 is a power-of-2 scale
            q = fminf(fmaxf(q, 0.f), 255.f);
            xi = (uint32_t)q;
        }
        int word = j >> 5, bit = j & 31;
        for (int s = 0; s < NS; ++s) ms[s][word] |= ((xi >> s) & 1u) << bit;
    }
    uint32_t* dst = xmask + (size_t)gid * (NS * 4);  // [b][sub][p][s][word]
    for (int s = 0; s < NS; ++s)
        for (int w2 = 0; w2 < 4; ++w2) dst[s * 4 + w2] = ms[s][w2];
}

// ---------------------------------------------------------------------------
// Pass 1: popcount everything, reduce max per (sub, sign). Exact integers.
// ---------------------------------------------------------------------------
__global__ __launch_bounds__(256) void k_pass1(const uint32_t* __restrict__ xmask,
                                               const uint32_t* __restrict__ wmask,
                                               uint32_t* __restrict__ maxv) {
    int sub = blockIdx.z;
    int b = blockIdx.y;
    int pt = blockIdx.x >> 2, ot = blockIdx.x & 3;
    int tid = threadIdx.x;
    int o = ot * 32 + (tid & 31);
    int p = pt * 8 + (tid >> 5);

    ulonglong2 xm[NS];
    const ulonglong2* xp =
        (const ulonglong2*)(xmask + ((size_t)(b * NSUB + sub) * PP + p) * NS * 4);
    for (int s = 0; s < NS; ++s) xm[s] = xp[s];

    ulonglong2 wmp[NT], wmn[NT];
    const ulonglong2* wp =
        (const ulonglong2*)(wmask + ((size_t)sub * COUT_ + o) * NT * 2 * 4);
    for (int t = 0; t < NT; ++t) { wmp[t] = wp[2 * t]; wmn[t] = wp[2 * t + 1]; }

    uint32_t mp = 0, mn = 0;
    for (int s = 0; s < NS; ++s)
        for (int t = 0; t < NT; ++t) {
            uint32_t pp = __popcll(xm[s].x & wmp[t].x) + __popcll(xm[s].y & wmp[t].y);
            uint32_t nn = __popcll(xm[s].x & wmn[t].x) + __popcll(xm[s].y & wmn[t].y);
            mp = max(mp, pp);
            mn = max(mn, nn);
        }

    __shared__ uint32_t rp[256], rn[256];
    rp[tid] = mp; rn[tid] = mn;
    __syncthreads();
    for (int s = 128; s > 0; s >>= 1) {
        if (tid < s) {
            rp[tid] = max(rp[tid], rp[tid + s]);
            rn[tid] = max(rn[tid], rn[tid + s]);
        }
        __syncthreads();
    }
    if (tid == 0) {
        atomicMax(&maxv[sub * 2 + 0], rp[0]);
        atomicMax(&maxv[sub * 2 + 1], rn[0]);
    }
}

// ---------------------------------------------------------------------------
// Build ADC LUTs in FLOAT64: Q(pr) = clip(rint(pr/step),0,15), step=max(vmax,1e-6)/15.
// f64 resolves real ties (pr*15 == vmax*(2k+1)) by round-half-even exactly,
// matching a float64 numpy golden; f32 can land 1 ulp off the tie.
// ---------------------------------------------------------------------------
__global__ void k_lut(const uint32_t* __restrict__ maxv,
                      double* __restrict__ steps,
                      uint8_t* __restrict__ lut) {
    int i = threadIdx.x;
    if (i < 18) {
        double vmaxd = fmax((double)maxv[i], 1e-6);
        steps[i] = vmaxd / 15.0;
    }
    for (int e = i; e < 18 * 129; e += 256) {
        int idx = e / 129;
        int pr = e % 129;
        double vmaxd = fmax((double)maxv[idx], 1e-6);
        double step = vmaxd / 15.0;
        double q = rint((double)pr / step);   // exact IEEE f64 div + half-even
        q = fmin(fmax(q, 0.0), 15.0);
        lut[idx * 132 + pr] = (uint8_t)q;
    }
}

// ---------------------------------------------------------------------------
// Pass 2: recompute popcounts, quantize via LDS LUT, integer-exact weighted sum,
// f64 step/scale arithmetic, cast to f32 at store.
// ---------------------------------------------------------------------------
__global__ __launch_bounds__(256) void k_pass2(const uint32_t* __restrict__ xmask,
                                               const uint32_t* __restrict__ wmask,
                                               const double* __restrict__ steps,
                                               const uint8_t* __restrict__ lut,
                                               const float* __restrict__ norm,
                                               float* __restrict__ out) {
    int b = blockIdx.y;
    int pt = blockIdx.x >> 2, ot = blockIdx.x & 3;
    int tid = threadIdx.x;
    int o = ot * 32 + (tid & 31);
    int p = pt * 8 + (tid >> 5);

    // stage LUTs to LDS, 4 replicas to spread bank pressure of u8 gathers
    __shared__ uint8_t llut[4 * 2376];
    {
        const uint32_t* l32 = (const uint32_t*)lut;
        uint32_t* s32 = (uint32_t*)llut;
        for (int i = tid; i < 594; i += 256) {
            uint32_t v = l32[i];
            for (int c = 0; c < 4; ++c) s32[c * 594 + i] = v;
        }
    }
    __syncthreads();
    const uint8_t* myl = llut + (tid & 3) * 2376;

    double acc = 0.0;
    for (int sub = 0; sub < NSUB; ++sub) {
        double stp = steps[sub * 2 + 0];
        double stn = steps[sub * 2 + 1];

        ulonglong2 xm[NS];
        const ulonglong2* xp =
            (const ulonglong2*)(xmask + ((size_t)(b * NSUB + sub) * PP + p) * NS * 4);
        for (int s = 0; s < NS; ++s) xm[s] = xp[s];

        ulonglong2 wmp[NT], wmn[NT];
        const ulonglong2* wp2 =
            (const ulonglong2*)(wmask + ((size_t)sub * COUT_ + o) * NT * 2 * 4);
        for (int t = 0; t < NT; ++t) { wmp[t] = wp2[2 * t]; wmn[t] = wp2[2 * t + 1]; }

        const uint8_t* lp = myl + sub * 264;   // [sub][sign][132]
        const uint8_t* ln = lp + 132;

        uint32_t Sp = 0, Sn = 0;
        for (int s = 0; s < NS; ++s)
            for (int t = 0; t < NT; ++t) {
                uint32_t pp = __popcll(xm[s].x & wmp[t].x) + __popcll(xm[s].y & wmp[t].y);
                uint32_t nn = __popcll(xm[s].x & wmn[t].x) + __popcll(xm[s].y & wmn[t].y);
                Sp += (uint32_t)lp[pp] << (s + t);
                Sn += (uint32_t)ln[nn] << (s + t);
            }
        acc += stp * (double)Sp - stn * (double)Sn;
    }
    double r = acc * (double)norm[o] / 255.0 / 256.0;
    out[((size_t)b * COUT_ + o) * PP + p] = (float)r;
    if (b == 0 && blockIdx.x == 0 && tid == 0)
        out[(size_t)B_ * COUT_ * PP] = 0.0f;   // adc_loss = 0
}

// ---------------------------------------------------------------------------
extern "C" void kernel_launch(void* const* d_in, const int* in_sizes, int n_in,
                              void* d_out, int out_size, void* d_ws, size_t ws_size,
                              hipStream_t stream) {
    const float* x = (const float*)d_in[0];
    const float* w = (const float*)d_in[1];
    float* out = (float*)d_out;
    char* ws = (char*)d_ws;

    float* norm = (float*)(ws + OFF_NORM);
    uint32_t* maxv = (uint32_t*)(ws + OFF_MAXV);
    double* steps = (double*)(ws + OFF_STEPS);
    uint8_t* lut = (uint8_t*)(ws + OFF_LUT);
    uint32_t* wmask = (uint32_t*)(ws + OFF_WMASK);
    uint32_t* xmask = (uint32_t*)(ws + OFF_XMASK);

    hipMemsetAsync(maxv, 0, 18 * sizeof(uint32_t), stream);
    k_prep_w<<<COUT_, 256, 0, stream>>>(w, norm, wmask);
    k_prep_x<<<(B_ * NSUB * PP + 255) / 256, 256, 0, stream>>>(x, xmask);
    k_pass1<<<dim3(512, B_, NSUB), 256, 0, stream>>>(xmask, wmask, maxv);
    k_lut<<<1, 256, 0, stream>>>(maxv, steps, lut);
    k_pass2<<<dim3(512, B_), 256, 0, stream>>>(xmask, wmask, steps, lut, norm, out);
}

// Round 3
// 239.780 us; speedup vs baseline: 1.5261x; 1.5261x over previous
//
#include <hip/hip_runtime.h>
#include <stdint.h>

// Problem constants
#define B_    2
#define CIN   128
#define HIMG  32
#define WIMG  32
#define COUT_ 128
#define PP    1024          // 32*32 output positions
#define FTOT  1152          // CIN*9
#define NSUB  9
#define CHUNK 128           // features per subarray
#define NS    8             // input bit streams
#define NT    8             // weight bit slices

// Workspace layout (bytes)
#define OFF_NORM   0                      // 128 f32
#define OFF_MAXV   512                    // 18 u32 (atomicMax targets)
#define OFF_STEPS  1024                   // 18 f64
#define OFF_LUT    2048                   // 18*132 u8 = 2376 (pad)
#define OFF_WMASK  8192                   // 9*128*64 u32 = 294912 B
#define OFF_XMASK  303104                 // 2*9*8*4*1024 u32 = 2359296 B

// ---------------------------------------------------------------------------
// Weight prep (unchanged from passing r2): per-o norm, f64 quantization,
// pos/neg 1-bit slices packed into 128-bit masks. wmask[sub][o][t][sign][word].
// ---------------------------------------------------------------------------
__global__ __launch_bounds__(256) void k_prep_w(const float* __restrict__ w,
                                                float* __restrict__ norm_out,
                                                uint32_t* __restrict__ wmask) {
    int o = blockIdx.x;
    int tid = threadIdx.x;
    __shared__ float red[256];
    __shared__ uint32_t lmask[NSUB * NT * 2 * 4];   // 576 u32
    for (int i = tid; i < NSUB * NT * 2 * 4; i += 256) lmask[i] = 0u;

    const float* wo = w + (size_t)o * FTOT;
    float m = 0.f;
    for (int f = tid; f < FTOT; f += 256) m = fmaxf(m, fabsf(wo[f]));
    red[tid] = m;
    __syncthreads();
    for (int s = 128; s > 0; s >>= 1) {
        if (tid < s) red[tid] = fmaxf(red[tid], red[tid + s]);
        __syncthreads();
    }
    float norm = red[0];
    if (tid == 0) norm_out[o] = norm;

    for (int f = tid; f < FTOT; f += 256) {
        double wi = rint(((double)wo[f] / (double)norm) * 255.0);
        int ip = (int)fmax(wi, 0.0);      // 0..255
        int in_ = (int)fmax(-wi, 0.0);    // 0..255
        int sub = f >> 7;
        int j = f & 127;
        int word = j >> 5, bit = j & 31;
        for (int t = 0; t < NT; ++t) {
            if ((ip >> t) & 1)
                atomicOr(&lmask[((sub * NT + t) * 2 + 0) * 4 + word], 1u << bit);
            if ((in_ >> t) & 1)
                atomicOr(&lmask[((sub * NT + t) * 2 + 1) * 4 + word], 1u << bit);
        }
    }
    __syncthreads();
    for (int i = tid; i < NSUB * NT * 2 * 4; i += 256) {
        int word = i & 3;
        int sign = (i >> 2) & 1;
        int t = (i >> 3) & 7;
        int sub = i >> 6;
        wmask[(((size_t)sub * COUT_ + o) * NT + t) * 2 * 4 + sign * 4 + word] = lmask[i];
    }
}

// ---------------------------------------------------------------------------
// Input prep: im2col + quantize + bit-pack. NEW layout: xmask[b][sub][s][word][p]
// so that pass1/pass2 (lane = p) load x-masks fully coalesced (4B/lane).
// ---------------------------------------------------------------------------
__global__ __launch_bounds__(256) void k_prep_x(const float* __restrict__ x,
                                                uint32_t* __restrict__ xmask) {
    int gid = blockIdx.x * 256 + threadIdx.x;    // B_*NSUB*PP = 18432
    if (gid >= B_ * NSUB * PP) return;
    int p = gid & 1023;
    int rest = gid >> 10;
    int sub = rest % NSUB;
    int b = rest / NSUB;
    int py = p >> 5, px = p & 31;

    uint32_t ms[NS][4] = {};
    #pragma unroll 4
    for (int j = 0; j < CHUNK; ++j) {
        int f = sub * CHUNK + j;
        int c = f / 9;
        int u = f % 9;
        int kh = u / 3, kw = u % 3;
        int y = py + kh - 1, xx = px + kw - 1;
        uint32_t xi = 0;
        if (y >= 0 && y < HIMG && xx >= 0 && xx < WIMG) {
            float v = x[(((size_t)b * CIN + c) * HIMG + y) * WIMG + xx];
            float q = rintf(v * 256.0f);   // exact: power-of-2 scale
            q = fminf(fmaxf(q, 0.f), 255.f);
            xi = (uint32_t)q;
        }
        int word = j >> 5, bit = j & 31;
        #pragma unroll
        for (int s = 0; s < NS; ++s) ms[s][word] |= ((xi >> s) & 1u) << bit;
    }
    uint32_t* dst = xmask + (size_t)(b * NSUB + sub) * (NS * 4) * PP + p;
    #pragma unroll
    for (int s = 0; s < NS; ++s)
        #pragma unroll
        for (int w2 = 0; w2 < 4; ++w2) dst[(s * 4 + w2) * PP] = ms[s][w2];
}

// ---------------------------------------------------------------------------
// popcount of 128-bit AND, x in VGPRs, w wave-uniform (SGPR-izable)
// ---------------------------------------------------------------------------
__device__ __forceinline__ uint32_t popc4(const uint32_t xv[4], const uint32_t wv[4]) {
    return __popc(xv[0] & wv[0]) + __popc(xv[1] & wv[1]) +
           __popc(xv[2] & wv[2]) + __popc(xv[3] & wv[3]);
}

// ---------------------------------------------------------------------------
// Pass 1: max popcount per (sub, sign). wave = (b, o, ptile); lane = p.
// ---------------------------------------------------------------------------
__global__ __launch_bounds__(256, 3) void k_pass1(const uint32_t* __restrict__ xmask,
                                                  const uint32_t* __restrict__ wmask,
                                                  uint32_t* __restrict__ maxv) {
    int tid = threadIdx.x;
    int lane = tid & 63;
    int wid = tid >> 6;
    int gw = blockIdx.x * 4 + wid;        // 0..4095
    int b  = gw >> 11;
    int o  = (gw >> 4) & 127;
    int pt = gw & 15;
    int p  = pt * 64 + lane;

    __shared__ uint32_t sred[4][NSUB][2];

    for (int sub = 0; sub < NSUB; ++sub) {
        int woff = __builtin_amdgcn_readfirstlane((sub * COUT_ + o) * 64);
        const uint32_t* wp = wmask + woff;
        uint32_t wm[2][NT][4];
        #pragma unroll
        for (int t = 0; t < NT; ++t)
            #pragma unroll
            for (int k = 0; k < 4; ++k) {
                wm[0][t][k] = wp[t * 8 + k];
                wm[1][t][k] = wp[t * 8 + 4 + k];
            }

        const uint32_t* xp = xmask + (size_t)(b * NSUB + sub) * (NS * 4) * PP + p;
        uint32_t xv[NS][4];
        #pragma unroll
        for (int s = 0; s < NS; ++s)
            #pragma unroll
            for (int k = 0; k < 4; ++k) xv[s][k] = xp[(s * 4 + k) * PP];

        uint32_t mp = 0, mn = 0;
        #pragma unroll
        for (int s = 0; s < NS; ++s)
            #pragma unroll
            for (int t = 0; t < NT; ++t) {
                mp = max(mp, popc4(xv[s], wm[0][t]));
                mn = max(mn, popc4(xv[s], wm[1][t]));
            }
        // wave butterfly reduce
        #pragma unroll
        for (int off = 32; off > 0; off >>= 1) {
            mp = max(mp, (uint32_t)__shfl_xor((int)mp, off));
            mn = max(mn, (uint32_t)__shfl_xor((int)mn, off));
        }
        if (lane == 0) { sred[wid][sub][0] = mp; sred[wid][sub][1] = mn; }
    }
    __syncthreads();
    if (tid < 18) {
        int sub = tid >> 1, sg = tid & 1;
        uint32_t m = max(max(sred[0][sub][sg], sred[1][sub][sg]),
                         max(sred[2][sub][sg], sred[3][sub][sg]));
        atomicMax(&maxv[tid], m);
    }
}

// ---------------------------------------------------------------------------
// Build ADC LUTs in FLOAT64 (tie-exact vs float64 numpy golden).
// ---------------------------------------------------------------------------
__global__ void k_lut(const uint32_t* __restrict__ maxv,
                      double* __restrict__ steps,
                      uint8_t* __restrict__ lut) {
    int i = threadIdx.x;
    if (i < 18) {
        double vmaxd = fmax((double)maxv[i], 1e-6);
        steps[i] = vmaxd / 15.0;
    }
    for (int e = i; e < 18 * 129; e += 256) {
        int idx = e / 129;
        int pr = e % 129;
        double vmaxd = fmax((double)maxv[idx], 1e-6);
        double step = vmaxd / 15.0;
        double q = rint((double)pr / step);
        q = fmin(fmax(q, 0.0), 15.0);
        lut[idx * 132 + pr] = (uint8_t)q;
    }
}

// ---------------------------------------------------------------------------
// Pass 2: recompute popcounts, LDS-LUT quantize, integer-exact weighted sum,
// f64 per-sub scaling. wave = (b, o, ptile); lane = p.
// ---------------------------------------------------------------------------
__global__ __launch_bounds__(256, 3) void k_pass2(const uint32_t* __restrict__ xmask,
                                                  const uint32_t* __restrict__ wmask,
                                                  const double* __restrict__ steps,
                                                  const uint8_t* __restrict__ lut,
                                                  const float* __restrict__ norm,
                                                  float* __restrict__ out) {
    int tid = threadIdx.x;
    int lane = tid & 63;
    int wid = tid >> 6;
    int gw = blockIdx.x * 4 + wid;
    int b  = gw >> 11;
    int o  = (gw >> 4) & 127;
    int pt = gw & 15;
    int p  = pt * 64 + lane;

    // LUT -> LDS, 4 replicas (594-word stride = 18-bank rotation)
    __shared__ uint8_t llut[4 * 2376];
    {
        const uint32_t* l32 = (const uint32_t*)lut;
        uint32_t* s32 = (uint32_t*)llut;
        for (int i = tid; i < 594; i += 256) {
            uint32_t v = l32[i];
            #pragma unroll
            for (int c = 0; c < 4; ++c) s32[c * 594 + i] = v;
        }
    }
    __syncthreads();
    const uint8_t* myl = llut + (lane & 3) * 2376;

    double acc = 0.0;
    for (int sub = 0; sub < NSUB; ++sub) {
        int woff = __builtin_amdgcn_readfirstlane((sub * COUT_ + o) * 64);
        const uint32_t* wp = wmask + woff;
        uint32_t wm[2][NT][4];
        #pragma unroll
        for (int t = 0; t < NT; ++t)
            #pragma unroll
            for (int k = 0; k < 4; ++k) {
                wm[0][t][k] = wp[t * 8 + k];
                wm[1][t][k] = wp[t * 8 + 4 + k];
            }

        const uint32_t* xp = xmask + (size_t)(b * NSUB + sub) * (NS * 4) * PP + p;
        uint32_t xv[NS][4];
        #pragma unroll
        for (int s = 0; s < NS; ++s)
            #pragma unroll
            for (int k = 0; k < 4; ++k) xv[s][k] = xp[(s * 4 + k) * PP];

        double stp = steps[sub * 2 + 0];
        double stn = steps[sub * 2 + 1];
        const uint8_t* lp = myl + sub * 264;   // [sub][sign][132]
        const uint8_t* ln = lp + 132;

        uint32_t Sp = 0, Sn = 0;
        #pragma unroll
        for (int s = 0; s < NS; ++s)
            #pragma unroll
            for (int t = 0; t < NT; ++t) {
                uint32_t pp = popc4(xv[s], wm[0][t]);
                uint32_t nn = popc4(xv[s], wm[1][t]);
                Sp += (uint32_t)lp[pp] << (s + t);
                Sn += (uint32_t)ln[nn] << (s + t);
            }
        acc += stp * (double)Sp - stn * (double)Sn;
    }
    double r = acc * (double)norm[o] / 255.0 / 256.0;
    out[((size_t)(b * COUT_ + o)) * PP + p] = (float)r;
    if (blockIdx.x == 0 && tid == 0)
        out[(size_t)B_ * COUT_ * PP] = 0.0f;   // adc_loss = 0
}

// ---------------------------------------------------------------------------
extern "C" void kernel_launch(void* const* d_in, const int* in_sizes, int n_in,
                              void* d_out, int out_size, void* d_ws, size_t ws_size,
                              hipStream_t stream) {
    const float* x = (const float*)d_in[0];
    const float* w = (const float*)d_in[1];
    float* out = (float*)d_out;
    char* ws = (char*)d_ws;

    float* norm = (float*)(ws + OFF_NORM);
    uint32_t* maxv = (uint32_t*)(ws + OFF_MAXV);
    double* steps = (double*)(ws + OFF_STEPS);
    uint8_t* lut = (uint8_t*)(ws + OFF_LUT);
    uint32_t* wmask = (uint32_t*)(ws + OFF_WMASK);
    uint32_t* xmask = (uint32_t*)(ws + OFF_XMASK);

    hipMemsetAsync(maxv, 0, 18 * sizeof(uint32_t), stream);
    k_prep_w<<<COUT_, 256, 0, stream>>>(w, norm, wmask);
    k_prep_x<<<(B_ * NSUB * PP + 255) / 256, 256, 0, stream>>>(x, xmask);
    k_pass1<<<1024, 256, 0, stream>>>(xmask, wmask, maxv);
    k_lut<<<1, 256, 0, stream>>>(maxv, steps, lut);
    k_pass2<<<1024, 256, 0, stream>>>(xmask, wmask, steps, lut, norm, out);
}

// Round 4
// 140.750 us; speedup vs baseline: 2.5998x; 1.7036x over previous
//
#include <hip/hip_runtime.h>
#include <stdint.h>

#define B_    2
#define CIN   128
#define HIMG  32
#define WIMG  32
#define COUT_ 128
#define PP    1024
#define FTOT  1152
#define NSUB  9
#define NS    8
#define NT    8

typedef int v4i __attribute__((ext_vector_type(4)));

// ws layout (bytes) — total ~2.66 MB (same footprint class as proven rounds)
#define OFF_NORM   0                      // 128 f32
#define OFF_MAXV   512                    // 18 u32
#define OFF_LUT    1024                   // 18*132 u8
#define OFF_WQP    4096                   // 128*1152 u8
#define OFF_WQN    (4096 + 147456)
#define OFF_XQ     (4096 + 2*147456)      // 2*1024*1152 u8

// ---------------------------------------------------------------------------
// Weight prep: per-o norm (f32 max), f64 quantization (matches np-f64 golden),
// store |wi| magnitudes as u8 per sign: wq[o][f].
// ---------------------------------------------------------------------------
__global__ __launch_bounds__(256) void k_prep_w(const float* __restrict__ w,
                                                float* __restrict__ norm_out,
                                                uint8_t* __restrict__ wqp,
                                                uint8_t* __restrict__ wqn) {
    int o = blockIdx.x, tid = threadIdx.x;
    __shared__ float red[256];
    const float* wo = w + (size_t)o * FTOT;
    float m = 0.f;
    for (int f = tid; f < FTOT; f += 256) m = fmaxf(m, fabsf(wo[f]));
    red[tid] = m;
    __syncthreads();
    for (int s2 = 128; s2 > 0; s2 >>= 1) {
        if (tid < s2) red[tid] = fmaxf(red[tid], red[tid + s2]);
        __syncthreads();
    }
    float norm = red[0];
    if (tid == 0) norm_out[o] = norm;
    for (int f = tid; f < FTOT; f += 256) {
        double wi = rint(((double)wo[f] / (double)norm) * 255.0);
        wqp[(size_t)o * FTOT + f] = (uint8_t)(int)fmax(wi, 0.0);
        wqn[(size_t)o * FTOT + f] = (uint8_t)(int)fmax(-wi, 0.0);
    }
}

// ---------------------------------------------------------------------------
// Input prep: im2col + unsigned fixed-point quantize, store xi bytes xq[b][p][f].
// Thread per (b, p, 16-feature group): 16 gathers -> one coalesced 16B store.
// ---------------------------------------------------------------------------
__global__ __launch_bounds__(256) void k_prep_x(const float* __restrict__ x,
                                                uint8_t* __restrict__ xq) {
    int gid = blockIdx.x * 256 + threadIdx.x;    // 2*1024*72 = 147456 exact
    int fg = gid % 72;
    int rest = gid / 72;
    int p = rest & 1023;
    int b = rest >> 10;
    int py = p >> 5, px = p & 31;
    uint32_t dw[4] = {0, 0, 0, 0};
    #pragma unroll
    for (int j = 0; j < 16; ++j) {
        int f = fg * 16 + j;
        int c = f / 9, u = f % 9;
        int kh = u / 3, kw = u % 3;
        int y = py + kh - 1, xx = px + kw - 1;
        uint32_t xi = 0;
        if (y >= 0 && y < HIMG && xx >= 0 && xx < WIMG) {
            float v = x[(((size_t)b * CIN + c) * HIMG + y) * WIMG + xx];
            float q = rintf(v * 256.0f);              // exact: power-of-2 scale
            q = fminf(fmaxf(q, 0.f), 255.f);
            xi = (uint32_t)q;
        }
        dw[j >> 2] |= xi << ((j & 3) * 8);
    }
    *reinterpret_cast<uint4*>(xq + (size_t)((b << 10) + p) * FTOT + fg * 16) =
        make_uint4(dw[0], dw[1], dw[2], dw[3]);
}

// Extract bit `sh` of each packed byte -> 0/1 bytes (i8 MFMA operand fragment).
__device__ __forceinline__ v4i bitsel(uint4 d, int sh) {
    v4i r;
    r[0] = (int)((d.x >> sh) & 0x01010101u);
    r[1] = (int)((d.y >> sh) & 0x01010101u);
    r[2] = (int)((d.z >> sh) & 0x01010101u);
    r[3] = (int)((d.w >> sh) & 0x01010101u);
    return r;
}

// ---------------------------------------------------------------------------
// Pass 1: max pr per (sub, sign) via MFMA. Block(512) = (b,ot,pt), wave = s.
// A = w bits (16 o x 64 k), B = x bits (64 k x 16 p), 2 MFMAs chain K=128.
// ---------------------------------------------------------------------------
__global__ __launch_bounds__(512) void k_max(const uint8_t* __restrict__ xq,
                                             const uint8_t* __restrict__ wqp,
                                             const uint8_t* __restrict__ wqn,
                                             uint32_t* __restrict__ maxv) {
    int tid = threadIdx.x, lane = tid & 63, wid = tid >> 6;
    int blk = blockIdx.x;
    int b = blk >> 9, r = blk & 511, ot = r >> 6, pt = r & 63;
    int s = wid;
    int col = lane & 15, kq = lane >> 4;
    int p = pt * 16 + col, oa = ot * 16 + col;
    __shared__ uint32_t smax[8][NSUB][2];

    const uint8_t* xbase = xq + (size_t)((b << 10) + p) * FTOT + kq * 16;
    const uint8_t* wpb = wqp + (size_t)oa * FTOT + kq * 16;
    const uint8_t* wnb = wqn + (size_t)oa * FTOT + kq * 16;

    for (int sub = 0; sub < NSUB; ++sub) {
        int fo = sub * 128;
        uint4 xg0 = *(const uint4*)(xbase + fo);
        uint4 xg1 = *(const uint4*)(xbase + fo + 64);
        v4i bf0 = bitsel(xg0, s), bf1 = bitsel(xg1, s);
        uint4 wp0 = *(const uint4*)(wpb + fo), wp1 = *(const uint4*)(wpb + fo + 64);
        uint4 wn0 = *(const uint4*)(wnb + fo), wn1 = *(const uint4*)(wnb + fo + 64);
        int mp = 0, mn = 0;
        #pragma unroll
        for (int t = 0; t < NT; ++t) {
            v4i acc = {0, 0, 0, 0};
            acc = __builtin_amdgcn_mfma_i32_16x16x64_i8(bitsel(wp0, t), bf0, acc, 0, 0, 0);
            acc = __builtin_amdgcn_mfma_i32_16x16x64_i8(bitsel(wp1, t), bf1, acc, 0, 0, 0);
            mp = max(max(acc[0], acc[1]), max(max(acc[2], acc[3]), mp));
            v4i acn = {0, 0, 0, 0};
            acn = __builtin_amdgcn_mfma_i32_16x16x64_i8(bitsel(wn0, t), bf0, acn, 0, 0, 0);
            acn = __builtin_amdgcn_mfma_i32_16x16x64_i8(bitsel(wn1, t), bf1, acn, 0, 0, 0);
            mn = max(max(acn[0], acn[1]), max(max(acn[2], acn[3]), mn));
        }
        #pragma unroll
        for (int off = 32; off > 0; off >>= 1) {
            mp = max(mp, __shfl_xor(mp, off));
            mn = max(mn, __shfl_xor(mn, off));
        }
        if (lane == 0) { smax[wid][sub][0] = (uint32_t)mp; smax[wid][sub][1] = (uint32_t)mn; }
    }
    __syncthreads();
    if (tid < 18) {
        int sub = tid >> 1, sg = tid & 1;
        uint32_t m = 0;
        #pragma unroll
        for (int w2 = 0; w2 < 8; ++w2) m = max(m, smax[w2][sub][sg]);
        atomicMax(&maxv[tid], m);
    }
}

// ---------------------------------------------------------------------------
// f64-exact ADC LUT (tie-exact vs float64 numpy golden).
// ---------------------------------------------------------------------------
__global__ void k_lut(const uint32_t* __restrict__ maxv, uint8_t* __restrict__ lut) {
    int i = threadIdx.x;
    for (int e = i; e < 18 * 129; e += 256) {
        int idx = e / 129, pr = e % 129;
        double vmaxd = fmax((double)maxv[idx], 1e-6);
        double step = vmaxd / 15.0;
        double q = rint((double)pr / step);
        q = fmin(fmax(q, 0.0), 15.0);
        lut[idx * 132 + pr] = (uint8_t)q;
    }
}

// ---------------------------------------------------------------------------
// Pass 2: MFMA pr -> LDS-LUT ADC codes -> exact integer weighted sums
// run = sum_sub (vmax_p*Sp - vmax_n*Sn); 8 s-waves reduced in LDS -> f32 out.
// ---------------------------------------------------------------------------
__global__ __launch_bounds__(512) void k_adc(const uint8_t* __restrict__ xq,
                                             const uint8_t* __restrict__ wqp,
                                             const uint8_t* __restrict__ wqn,
                                             const uint32_t* __restrict__ maxv,
                                             const uint8_t* __restrict__ lut,
                                             const float* __restrict__ norm,
                                             float* __restrict__ out) {
    int tid = threadIdx.x, lane = tid & 63, wid = tid >> 6;
    int blk = blockIdx.x;
    int b = blk >> 9, r = blk & 511, ot = r >> 6, pt = r & 63;
    int s = wid;
    int col = lane & 15, kq = lane >> 4;
    int p = pt * 16 + col, oa = ot * 16 + col;

    __shared__ uint8_t llut[4 * 2376];
    __shared__ int lred[8][64][4];
    {
        const uint32_t* l32 = (const uint32_t*)lut;
        uint32_t* s32 = (uint32_t*)llut;
        for (int i = tid; i < 594; i += 512) {
            uint32_t v = l32[i];
            #pragma unroll
            for (int c2 = 0; c2 < 4; ++c2) s32[c2 * 594 + i] = v;
        }
    }
    __syncthreads();
    const uint8_t* myl = llut + (lane & 3) * 2376;

    const uint8_t* xbase = xq + (size_t)((b << 10) + p) * FTOT + kq * 16;
    const uint8_t* wpb = wqp + (size_t)oa * FTOT + kq * 16;
    const uint8_t* wnb = wqn + (size_t)oa * FTOT + kq * 16;

    int run[4] = {0, 0, 0, 0};
    for (int sub = 0; sub < NSUB; ++sub) {
        int fo = sub * 128;
        uint4 xg0 = *(const uint4*)(xbase + fo);
        uint4 xg1 = *(const uint4*)(xbase + fo + 64);
        v4i bf0 = bitsel(xg0, s), bf1 = bitsel(xg1, s);
        uint4 wp0 = *(const uint4*)(wpb + fo), wp1 = *(const uint4*)(wpb + fo + 64);
        uint4 wn0 = *(const uint4*)(wnb + fo), wn1 = *(const uint4*)(wnb + fo + 64);
        const uint8_t* lp = myl + sub * 264;
        const uint8_t* ln = lp + 132;
        int vp = (int)maxv[sub * 2], vn = (int)maxv[sub * 2 + 1];
        uint32_t Sp[4] = {0, 0, 0, 0}, Sn[4] = {0, 0, 0, 0};
        #pragma unroll
        for (int t = 0; t < NT; ++t) {
            v4i acc = {0, 0, 0, 0};
            acc = __builtin_amdgcn_mfma_i32_16x16x64_i8(bitsel(wp0, t), bf0, acc, 0, 0, 0);
            acc = __builtin_amdgcn_mfma_i32_16x16x64_i8(bitsel(wp1, t), bf1, acc, 0, 0, 0);
            #pragma unroll
            for (int i = 0; i < 4; ++i) Sp[i] += (uint32_t)lp[acc[i]] << (s + t);
            v4i acn = {0, 0, 0, 0};
            acn = __builtin_amdgcn_mfma_i32_16x16x64_i8(bitsel(wn0, t), bf0, acn, 0, 0, 0);
            acn = __builtin_amdgcn_mfma_i32_16x16x64_i8(bitsel(wn1, t), bf1, acn, 0, 0, 0);
            #pragma unroll
            for (int i = 0; i < 4; ++i) Sn[i] += (uint32_t)ln[acn[i]] << (s + t);
        }
        #pragma unroll
        for (int i = 0; i < 4; ++i) run[i] += vp * (int)Sp[i] - vn * (int)Sn[i];
    }
    #pragma unroll
    for (int i = 0; i < 4; ++i) lred[wid][lane][i] = run[i];
    __syncthreads();
    if (tid < 256) {
        int lane2 = tid >> 2, i = tid & 3;
        long long s64 = 0;
        #pragma unroll
        for (int w2 = 0; w2 < 8; ++w2) s64 += (long long)lred[w2][lane2][i];
        int o = ot * 16 + (lane2 >> 4) * 4 + i;      // C/D: row=(lane>>4)*4+reg [m89]
        int pp2 = pt * 16 + (lane2 & 15);            // C/D: col=lane&15
        double v = (double)s64 * (double)norm[o] / 15.0 / 255.0 / 256.0;
        out[((size_t)(b * COUT_ + o)) * PP + pp2] = (float)v;
    }
    if (blk == 0 && tid == 0) out[(size_t)B_ * COUT_ * PP] = 0.0f;   // adc_loss
}

// ---------------------------------------------------------------------------
extern "C" void kernel_launch(void* const* d_in, const int* in_sizes, int n_in,
                              void* d_out, int out_size, void* d_ws, size_t ws_size,
                              hipStream_t stream) {
    const float* x = (const float*)d_in[0];
    const float* w = (const float*)d_in[1];
    float* out = (float*)d_out;
    char* ws = (char*)d_ws;

    float* norm = (float*)(ws + OFF_NORM);
    uint32_t* maxv = (uint32_t*)(ws + OFF_MAXV);
    uint8_t* lut = (uint8_t*)(ws + OFF_LUT);
    uint8_t* wqp = (uint8_t*)(ws + OFF_WQP);
    uint8_t* wqn = (uint8_t*)(ws + OFF_WQN);
    uint8_t* xq  = (uint8_t*)(ws + OFF_XQ);

    hipMemsetAsync(maxv, 0, 18 * sizeof(uint32_t), stream);
    k_prep_w<<<128, 256, 0, stream>>>(w, norm, wqp, wqn);
    k_prep_x<<<576, 256, 0, stream>>>(x, xq);
    k_max<<<1024, 512, 0, stream>>>(xq, wqp, wqn, maxv);
    k_lut<<<1, 256, 0, stream>>>(maxv, lut);
    k_adc<<<1024, 512, 0, stream>>>(xq, wqp, wqn, maxv, lut, norm, out);
}